// Round 7
// baseline (219.697 us; speedup 1.0000x reference)
//
#include <hip/hip_runtime.h>
#include <hip/hip_bf16.h>
#include <math.h>

typedef __bf16 bf16;
typedef __bf16 bf16x4 __attribute__((ext_vector_type(4)));
typedef __bf16 bf16x8 __attribute__((ext_vector_type(8)));
typedef float  f32x4  __attribute__((ext_vector_type(4)));
typedef unsigned u32x2 __attribute__((ext_vector_type(2)));
typedef unsigned u32x4 __attribute__((ext_vector_type(4)));

#define T_SEQ 2048
#define E_DIM 1024
#define H_NUM 16
#define D_DIM 64
#define NDELTA 4095
#define LOG2E 1.4426950408889634f

__device__ __forceinline__ void gld16(const bf16* g, bf16* l) {
  __builtin_amdgcn_global_load_lds((__attribute__((address_space(1))) void*)(g),
                                   (__attribute__((address_space(3))) void*)(l), 16, 0, 0);
}

// in-register qd-group exchange via official gfx950 builtins
__device__ __forceinline__ void qswap(unsigned &a, unsigned &b) {
  u32x2 t  = __builtin_amdgcn_permlane32_swap(a, b, false, false);
  u32x2 t2 = __builtin_amdgcn_permlane16_swap(t[0], t[1], false, false);
  a = t2[0]; b = t2[1];
}

// ---------------- fused fp32->bf16 cast + gate (one block per bt row) ----------------
__global__ __launch_bounds__(256)
void cast_gate_kernel(const float* __restrict__ hs, bf16* __restrict__ hsb,
                      const float* __restrict__ gru_w, const float* __restrict__ gru_b,
                      const float* __restrict__ gconst, float* __restrict__ gate)
{
  __shared__ float w[512];
  const int tid = threadIdx.x;
  const int bt  = blockIdx.x;
  w[tid]       = gru_w[tid];
  w[tid + 256] = gru_w[tid + 256];
  __syncthreads();

  const int i = bt * 256 + tid;
  const float4 xv = reinterpret_cast<const float4*>(hs)[i];
  bf16x4 o;
  o[0] = (bf16)xv.x; o[1] = (bf16)xv.y; o[2] = (bf16)xv.z; o[3] = (bf16)xv.w;
  reinterpret_cast<bf16x4*>(hsb)[i] = o;

  const int h  = tid >> 4;
  const int d0 = (tid & 15) * 4;
  float acc[8];
#pragma unroll
  for (int e = 0; e < 8; e++) {
    acc[e] = xv.x * w[e*64+d0] + xv.y * w[e*64+d0+1]
           + xv.z * w[e*64+d0+2] + xv.w * w[e*64+d0+3];
  }
#pragma unroll
  for (int e = 0; e < 8; e++) {
    float v = acc[e];
    v += __shfl_xor(v, 1);
    v += __shfl_xor(v, 2);
    v += __shfl_xor(v, 4);
    v += __shfl_xor(v, 8);
    acc[e] = v;
  }
  if ((tid & 15) == 0) {
    float p0 = acc[0]+acc[1]+acc[2]+acc[3] + gru_b[0]+gru_b[1]+gru_b[2]+gru_b[3];
    float p1 = acc[4]+acc[5]+acc[6]+acc[7] + gru_b[4]+gru_b[5]+gru_b[6]+gru_b[7];
    float ga = 1.0f / (1.0f + expf(-p0));
    float gb = 1.0f / (1.0f + expf(-p1));
    float g = (ga * (gb * gconst[h] - 1.0f) + 2.0f) * LOG2E;
    int bb = bt >> 11;
    int t  = bt & (T_SEQ - 1);
    gate[((size_t)(bb * H_NUM + h)) * T_SEQ + t] = g;
  }
}

// ---------------- weight casts (y=0..3) + position-bias table (y=4) ----------------
__global__ void cast_w_kernel(const float* __restrict__ q_w, const float* __restrict__ k_w,
                              const float* __restrict__ v_w, const float* __restrict__ o_w,
                              bf16* __restrict__ wcat, bf16* __restrict__ wob,
                              const float* __restrict__ rel_embed, float* __restrict__ pbt) {
  int sel = blockIdx.y;
  int tid = threadIdx.x;
  if (sel == 4) {
    int dd = blockIdx.x * 256 + tid;
    if (blockIdx.x >= 16 || dd >= NDELTA) return;
    int delta = dd - (T_SEQ - 1);
    int bucket = (delta > 0) ? 160 : 0;
    int rel = abs(delta);
    int v;
    if (rel < 80) {
      v = rel;
    } else {
      float rf = (float)(rel < 1 ? 1 : rel);
      float lf = logf(rf / 80.0f) * (80.0f / 2.302585092994046f);
      int lg = 80 + (int)lf;
      v = lg < 159 ? lg : 159;
    }
    bucket += v;
#pragma unroll
    for (int h = 0; h < H_NUM; h++)
      pbt[h * NDELTA + dd] = rel_embed[bucket * H_NUM + h];
    return;
  }
  int i = blockIdx.x * 256 + tid;
  const float* src = (sel == 0) ? q_w : (sel == 1) ? k_w : (sel == 2) ? v_w : o_w;
  bf16* dst = (sel < 3) ? (wcat + (size_t)sel * 1048576) : wob;
  const float4 v = reinterpret_cast<const float4*>(src)[i];
  bf16x4 o;
  o[0] = (bf16)v.x; o[1] = (bf16)v.y; o[2] = (bf16)v.z; o[3] = (bf16)v.w;
  reinterpret_cast<bf16x4*>(dst)[i] = o;
}

// ---------------- GEMM v3: BK=64 + both-sides XOR chunk swizzle ----------------
// LDS [128][64] linear (gld16-compatible). Staging: lane l of each 8-row group
// sources global chunk ((l&7)^(l>>3)) so LDS[r][c] = G[r][c ^ (r&7)] (chunks of
// 8 bf16). Frag read for global chunk j of row R reads LDS chunk j ^ (R&7):
// bank window 4*((kk*4+qd)^(lm&7)) -> 8 lanes per window = b128 floor,
// conflict-free (the old [128][32] layout was 8-way conflicted, m98 pattern).
// BK=64 also halves barrier count (16 sync points vs 32).
template<int MODE, int N_TOTAL>
__global__ __launch_bounds__(256)
void gemm2_kernel(const bf16* __restrict__ A, const bf16* __restrict__ W,
                  const float* __restrict__ b0, const float* __restrict__ b1,
                  const float* __restrict__ b2, float qalpha,
                  void* __restrict__ out0, void* __restrict__ out1, void* __restrict__ out2)
{
  __shared__ bf16 As[128 * 64];
  __shared__ bf16 Bs[128 * 64];
  const int tid  = threadIdx.x;
  const int lane = tid & 63;
  const int wave = tid >> 6;
  const int m0 = blockIdx.y * 128;
  const int n0 = blockIdx.x * 128;
  const int wm = (wave >> 1) * 64;
  const int wn = (wave & 1) * 64;
  const int qd = lane >> 4;
  const int lm = lane & 15;

  // staging: wave w covers rows [w*32, w*32+32), 4 gld16 per operand (8 rows each)
  const int srow8  = lane >> 3;                     // row within 8-row group
  const int schunk = ((lane & 7) ^ srow8) * 8;      // swizzled source chunk (elems)
  const bf16* gA = A + (size_t)(m0 + wave * 32 + srow8) * 1024 + schunk;
  const bf16* gB = W + (size_t)(n0 + wave * 32 + srow8) * 1024 + schunk;
  bf16* lA = As + wave * 32 * 64;
  bf16* lB = Bs + wave * 32 * 64;

  f32x4 acc[4][4] = {};
  const int xs = lm & 7;   // read-side XOR (R&7 == lm&7 for rows wm+i*16+lm)

  for (int k0 = 0; k0 < 1024; k0 += 64) {
#pragma unroll
    for (int j = 0; j < 4; j++) {
      gld16(gA + (size_t)j * 8 * 1024 + k0, lA + j * 8 * 64);
      gld16(gB + (size_t)j * 8 * 1024 + k0, lB + j * 8 * 64);
    }
    __syncthreads();   // drains vmcnt -> LDS tiles valid
    bf16x8 af[4][2], bfr[4][2];
#pragma unroll
    for (int i = 0; i < 4; i++) {
#pragma unroll
      for (int kk = 0; kk < 2; kk++) {
        af[i][kk]  = *(const bf16x8*)&As[(wm + i * 16 + lm) * 64 + (((kk * 4 + qd) ^ xs) * 8)];
        bfr[i][kk] = *(const bf16x8*)&Bs[(wn + i * 16 + lm) * 64 + (((kk * 4 + qd) ^ xs) * 8)];
      }
    }
#pragma unroll
    for (int kk = 0; kk < 2; kk++)
#pragma unroll
      for (int im = 0; im < 4; im++)
#pragma unroll
        for (int in = 0; in < 4; in++)
          acc[im][in] = __builtin_amdgcn_mfma_f32_16x16x32_bf16(af[im][kk], bfr[in][kk], acc[im][in], 0, 0, 0);
    __syncthreads();   // frag reads done before next staging overwrites
  }

  const int seg = n0 >> 10;
  const float* bias = (MODE == 0) ? b0 : (seg == 0 ? b0 : (seg == 1 ? b1 : b2));
  const float alpha = (MODE == 1 && seg == 0) ? qalpha : 1.0f;

#pragma unroll
  for (int im = 0; im < 4; im++) {
#pragma unroll
    for (int in = 0; in < 4; in++) {
      const int n  = n0 + wn + in * 16 + lm;
      const int n1 = n & 1023;
      const float bv = bias[n1];
      const int mb = m0 + wm + im * 16 + qd * 4;
      if (MODE == 0) {
        float* o = (float*)out0;
#pragma unroll
        for (int r = 0; r < 4; r++)
          o[(size_t)(mb + r) * 1024 + n1] = acc[im][in][r] + bv;
      } else if (seg == 2) {
        const int bb = mb >> 11;
        const int t  = mb & 2047;
        bf16x4 pk;
#pragma unroll
        for (int r = 0; r < 4; r++) pk[r] = (bf16)(acc[im][in][r] + bv);
        *(bf16x4*)&((bf16*)out2)[((size_t)(bb * 1024 + n1)) * 2048 + t] = pk;
      } else {
        bf16* o = (bf16*)(seg == 0 ? out0 : out1);
#pragma unroll
        for (int r = 0; r < 4; r++)
          o[(size_t)(mb + r) * 1024 + n1] = (bf16)((acc[im][in][r] + bv) * alpha);
      }
    }
  }
}

// ---------------- O-projection GEMM: 64x128 tile -> grid (8,64)=512 blocks (2/CU) ----------------
__global__ __launch_bounds__(256)
void gemm_o_kernel(const bf16* __restrict__ A, const bf16* __restrict__ W,
                   const float* __restrict__ bias, float* __restrict__ out)
{
  __shared__ bf16 As[64 * 32];
  __shared__ bf16 Bs[128 * 32];
  const int tid  = threadIdx.x;
  const int lane = tid & 63;
  const int wave = tid >> 6;
  const int m0 = blockIdx.y * 64;
  const int n0 = blockIdx.x * 128;
  const int wm = (wave >> 1) * 32;
  const int wn = (wave & 1) * 64;
  const int qd = lane >> 4;
  const int lm = lane & 15;

  const int row4 = lane >> 2;
  const int col8 = (lane & 3) * 8;
  const bf16* gA0 = A + (size_t)(m0 + wave * 16 + row4) * 1024 + col8;
  const bf16* gB0 = W + (size_t)(n0 + wave * 32 + row4) * 1024 + col8;
  const bf16* gB1 = gB0 + (size_t)16 * 1024;
  bf16* lA0 = As + wave * 16 * 32;
  bf16* lB0 = Bs + (wave * 2 + 0) * 512;
  bf16* lB1 = Bs + (wave * 2 + 1) * 512;

  f32x4 acc[2][4] = {};

  for (int k0 = 0; k0 < 1024; k0 += 32) {
    gld16(gA0 + k0, lA0);
    gld16(gB0 + k0, lB0);
    gld16(gB1 + k0, lB1);
    __syncthreads();
    bf16x8 af[2], bfr[4];
#pragma unroll
    for (int i = 0; i < 2; i++)
      af[i]  = *(const bf16x8*)&As[(wm + i * 16 + lm) * 32 + qd * 8];
#pragma unroll
    for (int i = 0; i < 4; i++)
      bfr[i] = *(const bf16x8*)&Bs[(wn + i * 16 + lm) * 32 + qd * 8];
#pragma unroll
    for (int im = 0; im < 2; im++)
#pragma unroll
      for (int in = 0; in < 4; in++)
        acc[im][in] = __builtin_amdgcn_mfma_f32_16x16x32_bf16(af[im], bfr[in], acc[im][in], 0, 0, 0);
    __syncthreads();
  }

#pragma unroll
  for (int im = 0; im < 2; im++) {
#pragma unroll
    for (int in = 0; in < 4; in++) {
      const int n  = n0 + wn + in * 16 + lm;
      const float bv = bias[n];
      const int mb = m0 + wm + im * 16 + qd * 4;
#pragma unroll
      for (int r = 0; r < 4; r++)
        out[(size_t)(mb + r) * 1024 + n] = acc[im][in][r] + bv;
    }
  }
}

// ---------------- flash attention (round-2 exact: LDS pbs + in-register P redistribution) ----------------
#define LK 72
__global__ __launch_bounds__(256)
void attn3_kernel(const bf16* __restrict__ Qg, const bf16* __restrict__ Kg,
                  const bf16* __restrict__ Vtg, const float* __restrict__ gate,
                  const float* __restrict__ pbt, bf16* __restrict__ ctx)
{
  __shared__ bf16 Ks[2][64 * LK];
  __shared__ bf16 Vs[2][64 * LK];
  __shared__ float pbs[2176];

  const int t0 = blockIdx.x * 128;
  const int h  = blockIdx.y;
  const int b  = blockIdx.z;
  const int tid  = threadIdx.x;
  const int lane = tid & 63;
  const int wave = tid >> 6;
  const int qd = lane >> 4;
  const int lm = lane & 15;

  for (int i = tid; i < 2176; i += 256) {
    int idx = i - t0 + 1920;
    pbs[i] = (idx >= 0 && idx < NDELTA) ? pbt[h * NDELTA + idx] : 0.0f;
  }

  bf16x8 qf[2][2];
  float g[2];
#pragma unroll
  for (int nb = 0; nb < 2; nb++) {
    const int q = t0 + wave * 32 + nb * 16 + lm;
    const bf16* qrow = Qg + (size_t)(b * T_SEQ + q) * E_DIM + h * D_DIM;
    qf[nb][0] = *(const bf16x8*)(qrow + qd * 8);
    qf[nb][1] = *(const bf16x8*)(qrow + 32 + qd * 8);
    g[nb] = gate[((size_t)(b * H_NUM + h)) * T_SEQ + q];
  }

  const int srow = tid >> 2;
  const int scol = (tid & 3) * 16;
  const bf16* kgp = Kg  + ((size_t)(b * T_SEQ) + srow) * E_DIM + h * D_DIM + scol;
  const bf16* vgp = Vtg + ((size_t)(b * 1024) + h * D_DIM + srow) * T_SEQ + scol;

  {
    bf16x8 a0 = *(const bf16x8*)kgp;
    bf16x8 a1 = *(const bf16x8*)(kgp + 8);
    bf16x8 c0 = *(const bf16x8*)vgp;
    bf16x8 c1 = *(const bf16x8*)(vgp + 8);
    *(bf16x8*)&Ks[0][srow * LK + scol]     = a0;
    *(bf16x8*)&Ks[0][srow * LK + scol + 8] = a1;
    *(bf16x8*)&Vs[0][srow * LK + scol]     = c0;
    *(bf16x8*)&Vs[0][srow * LK + scol + 8] = c1;
  }
  __syncthreads();

  f32x4 o[4][2] = {};
  float li[2] = {0.0f, 0.0f};

  for (int it = 0; it < T_SEQ / 64; it++) {
    const int s0 = it * 64;
    const int buf = it & 1;
    const bool more = (it + 1 < T_SEQ / 64);
    bf16x8 nk0, nk1, nv0, nv1;
    if (more) {
      const bf16* kn = kgp + (size_t)(s0 + 64) * E_DIM;
      const bf16* vn = vgp + (s0 + 64);
      nk0 = *(const bf16x8*)kn; nk1 = *(const bf16x8*)(kn + 8);
      nv0 = *(const bf16x8*)vn; nv1 = *(const bf16x8*)(vn + 8);
    }

    bf16x8 kf[4][2];
#pragma unroll
    for (int mb = 0; mb < 4; mb++) {
      kf[mb][0] = *(const bf16x8*)&Ks[buf][(16 * mb + lm) * LK + qd * 8];
      kf[mb][1] = *(const bf16x8*)&Ks[buf][(16 * mb + lm) * LK + 32 + qd * 8];
    }

    bf16x8 pf[2][2];
#pragma unroll
    for (int nb = 0; nb < 2; nb++) {
      f32x4 sc[4];
#pragma unroll
      for (int mb = 0; mb < 4; mb++) {
        f32x4 t = {};
        t = __builtin_amdgcn_mfma_f32_16x16x32_bf16(kf[mb][0], qf[nb][0], t, 0, 0, 0);
        t = __builtin_amdgcn_mfma_f32_16x16x32_bf16(kf[mb][1], qf[nb][1], t, 0, 0, 0);
        sc[mb] = t;
      }
      const int ib = s0 + 4 * qd + 127 - (wave * 32 + nb * 16 + lm);
      float rs = 0.0f;
      unsigned wlo[4], whi[4];
#pragma unroll
      for (int mb = 0; mb < 4; mb++) {
        bf16x4 pk;
#pragma unroll
        for (int r = 0; r < 4; r++) {
          float p = __builtin_amdgcn_exp2f(sc[mb][r] + g[nb] * pbs[ib + 16 * mb + r]);
          rs += p;
          pk[r] = (bf16)p;
        }
        u32x2 pw = __builtin_bit_cast(u32x2, pk);
        wlo[mb] = pw[0]; whi[mb] = pw[1];
      }
      li[nb] += rs;
      unsigned a0 = wlo[0], b0v = wlo[1], a1 = whi[0], b1v = whi[1];
      qswap(a0, b0v);
      qswap(a1, b1v);
      u32x4 h0; h0[0] = a0; h0[1] = a1; h0[2] = b0v; h0[3] = b1v;
      pf[nb][0] = __builtin_bit_cast(bf16x8, h0);
      unsigned c0 = wlo[2], d0v = wlo[3], c1 = whi[2], d1v = whi[3];
      qswap(c0, d0v);
      qswap(c1, d1v);
      u32x4 h1; h1[0] = c0; h1[1] = c1; h1[2] = d0v; h1[3] = d1v;
      pf[nb][1] = __builtin_bit_cast(bf16x8, h1);
    }

#pragma unroll
    for (int db = 0; db < 4; db++) {
      bf16x8 vf0 = *(const bf16x8*)&Vs[buf][(16 * db + lm) * LK + qd * 8];
      bf16x8 vf1 = *(const bf16x8*)&Vs[buf][(16 * db + lm) * LK + 32 + qd * 8];
#pragma unroll
      for (int nb = 0; nb < 2; nb++) {
        o[db][nb] = __builtin_amdgcn_mfma_f32_16x16x32_bf16(vf0, pf[nb][0], o[db][nb], 0, 0, 0);
        o[db][nb] = __builtin_amdgcn_mfma_f32_16x16x32_bf16(vf1, pf[nb][1], o[db][nb], 0, 0, 0);
      }
    }
    if (more) {
      *(bf16x8*)&Ks[buf ^ 1][srow * LK + scol]     = nk0;
      *(bf16x8*)&Ks[buf ^ 1][srow * LK + scol + 8] = nk1;
      *(bf16x8*)&Vs[buf ^ 1][srow * LK + scol]     = nv0;
      *(bf16x8*)&Vs[buf ^ 1][srow * LK + scol + 8] = nv1;
    }
    __syncthreads();
  }

#pragma unroll
  for (int nb = 0; nb < 2; nb++) {
    li[nb] += __shfl_xor(li[nb], 16);
    li[nb] += __shfl_xor(li[nb], 32);
  }
#pragma unroll
  for (int nb = 0; nb < 2; nb++) {
    const float inv = 1.0f / li[nb];
    const int q = t0 + wave * 32 + nb * 16 + lm;
    bf16* obase = ctx + (size_t)(b * T_SEQ + q) * E_DIM + h * D_DIM + 4 * qd;
#pragma unroll
    for (int db = 0; db < 4; db++) {
      bf16x4 ov;
      ov[0] = (bf16)(o[db][nb][0] * inv); ov[1] = (bf16)(o[db][nb][1] * inv);
      ov[2] = (bf16)(o[db][nb][2] * inv); ov[3] = (bf16)(o[db][nb][3] * inv);
      *(bf16x4*)&obase[16 * db] = ov;
    }
  }
}

// ---------------- orchestration ----------------
extern "C" void kernel_launch(void* const* d_in, const int* in_sizes, int n_in,
                              void* d_out, int out_size, void* d_ws, size_t ws_size,
                              hipStream_t stream)
{
  const float* hs     = (const float*)d_in[0];
  const float* q_w    = (const float*)d_in[1];
  const float* q_b    = (const float*)d_in[2];
  const float* k_w    = (const float*)d_in[3];
  const float* k_b    = (const float*)d_in[4];
  const float* v_w    = (const float*)d_in[5];
  const float* v_b    = (const float*)d_in[6];
  const float* out_w  = (const float*)d_in[7];
  const float* out_b  = (const float*)d_in[8];
  const float* rel    = (const float*)d_in[9];
  const float* gconst = (const float*)d_in[10];
  const float* gru_w  = (const float*)d_in[11];
  const float* gru_b  = (const float*)d_in[12];

  char* p = (char*)d_ws;
  bf16* hsb  = (bf16*)p; p += (size_t)4096 * 1024 * 2;
  bf16* wcat = (bf16*)p; p += (size_t)3072 * 1024 * 2;
  bf16* wob  = (bf16*)p; p += (size_t)1024 * 1024 * 2;
  bf16* Qb   = (bf16*)p; p += (size_t)4096 * 1024 * 2;
  bf16* Kb   = (bf16*)p; p += (size_t)4096 * 1024 * 2;
  bf16* Vtb  = (bf16*)p; p += (size_t)2048 * 2048 * 2;
  bf16* ctxb = (bf16*)p; p += (size_t)4096 * 1024 * 2;
  float* gatep = (float*)p; p += (size_t)2 * H_NUM * T_SEQ * 4;
  float* pbt   = (float*)p; p += (size_t)H_NUM * NDELTA * 4;

  cast_gate_kernel<<<4096, 256, 0, stream>>>(hs, hsb, gru_w, gru_b, gconst, gatep);
  cast_w_kernel<<<dim3(1024, 5), 256, 0, stream>>>(q_w, k_w, v_w, out_w, wcat, wob, rel, pbt);

  const float qalpha = 0.125f * LOG2E;
  gemm2_kernel<1, 3072><<<dim3(24, 32), 256, 0, stream>>>(
      hsb, wcat, q_b, k_b, v_b, qalpha, Qb, Kb, Vtb);

  attn3_kernel<<<dim3(T_SEQ / 128, H_NUM, 2), 256, 0, stream>>>(Qb, Kb, Vtb, gatep, pbt, ctxb);

  gemm_o_kernel<<<dim3(8, 64), 256, 0, stream>>>(ctxb, wob, out_b, (float*)d_out);
}

// Round 9
// 217.073 us; speedup vs baseline: 1.0121x; 1.0121x over previous
//
#include <hip/hip_runtime.h>
#include <hip/hip_bf16.h>
#include <math.h>

typedef __bf16 bf16;
typedef __bf16 bf16x4 __attribute__((ext_vector_type(4)));
typedef __bf16 bf16x8 __attribute__((ext_vector_type(8)));
typedef float  f32x4  __attribute__((ext_vector_type(4)));
typedef unsigned u32x2 __attribute__((ext_vector_type(2)));
typedef unsigned u32x4 __attribute__((ext_vector_type(4)));

#define T_SEQ 2048
#define E_DIM 1024
#define H_NUM 16
#define D_DIM 64
#define NDELTA 4095
#define LOG2E 1.4426950408889634f

__device__ __forceinline__ void gld16(const bf16* g, bf16* l) {
  __builtin_amdgcn_global_load_lds((__attribute__((address_space(1))) void*)(g),
                                   (__attribute__((address_space(3))) void*)(l), 16, 0, 0);
}

// in-register qd-group exchange via official gfx950 builtins
__device__ __forceinline__ void qswap(unsigned &a, unsigned &b) {
  u32x2 t  = __builtin_amdgcn_permlane32_swap(a, b, false, false);
  u32x2 t2 = __builtin_amdgcn_permlane16_swap(t[0], t[1], false, false);
  a = t2[0]; b = t2[1];
}

// ---------------- fused fp32->bf16 cast + gate (one block per bt row) ----------------
__global__ __launch_bounds__(256)
void cast_gate_kernel(const float* __restrict__ hs, bf16* __restrict__ hsb,
                      const float* __restrict__ gru_w, const float* __restrict__ gru_b,
                      const float* __restrict__ gconst, float* __restrict__ gate)
{
  __shared__ float w[512];
  const int tid = threadIdx.x;
  const int bt  = blockIdx.x;
  w[tid]       = gru_w[tid];
  w[tid + 256] = gru_w[tid + 256];
  __syncthreads();

  const int i = bt * 256 + tid;
  const float4 xv = reinterpret_cast<const float4*>(hs)[i];
  bf16x4 o;
  o[0] = (bf16)xv.x; o[1] = (bf16)xv.y; o[2] = (bf16)xv.z; o[3] = (bf16)xv.w;
  reinterpret_cast<bf16x4*>(hsb)[i] = o;

  const int h  = tid >> 4;
  const int d0 = (tid & 15) * 4;
  float acc[8];
#pragma unroll
  for (int e = 0; e < 8; e++) {
    acc[e] = xv.x * w[e*64+d0] + xv.y * w[e*64+d0+1]
           + xv.z * w[e*64+d0+2] + xv.w * w[e*64+d0+3];
  }
#pragma unroll
  for (int e = 0; e < 8; e++) {
    float v = acc[e];
    v += __shfl_xor(v, 1);
    v += __shfl_xor(v, 2);
    v += __shfl_xor(v, 4);
    v += __shfl_xor(v, 8);
    acc[e] = v;
  }
  if ((tid & 15) == 0) {
    float p0 = acc[0]+acc[1]+acc[2]+acc[3] + gru_b[0]+gru_b[1]+gru_b[2]+gru_b[3];
    float p1 = acc[4]+acc[5]+acc[6]+acc[7] + gru_b[4]+gru_b[5]+gru_b[6]+gru_b[7];
    float ga = 1.0f / (1.0f + expf(-p0));
    float gb = 1.0f / (1.0f + expf(-p1));
    float g = (ga * (gb * gconst[h] - 1.0f) + 2.0f) * LOG2E;
    int bb = bt >> 11;
    int t  = bt & (T_SEQ - 1);
    gate[((size_t)(bb * H_NUM + h)) * T_SEQ + t] = g;
  }
}

// ---------------- weight casts (y=0..3) + position-bias table (y=4) ----------------
__global__ void cast_w_kernel(const float* __restrict__ q_w, const float* __restrict__ k_w,
                              const float* __restrict__ v_w, const float* __restrict__ o_w,
                              bf16* __restrict__ wcat, bf16* __restrict__ wob,
                              const float* __restrict__ rel_embed, float* __restrict__ pbt) {
  int sel = blockIdx.y;
  int tid = threadIdx.x;
  if (sel == 4) {
    int dd = blockIdx.x * 256 + tid;
    if (blockIdx.x >= 16 || dd >= NDELTA) return;
    int delta = dd - (T_SEQ - 1);
    int bucket = (delta > 0) ? 160 : 0;
    int rel = abs(delta);
    int v;
    if (rel < 80) {
      v = rel;
    } else {
      float rf = (float)(rel < 1 ? 1 : rel);
      float lf = logf(rf / 80.0f) * (80.0f / 2.302585092994046f);
      int lg = 80 + (int)lf;
      v = lg < 159 ? lg : 159;
    }
    bucket += v;
#pragma unroll
    for (int h = 0; h < H_NUM; h++)
      pbt[h * NDELTA + dd] = rel_embed[bucket * H_NUM + h];
    return;
  }
  int i = blockIdx.x * 256 + tid;
  const float* src = (sel == 0) ? q_w : (sel == 1) ? k_w : (sel == 2) ? v_w : o_w;
  bf16* dst = (sel < 3) ? (wcat + (size_t)sel * 1048576) : wob;
  const float4 v = reinterpret_cast<const float4*>(src)[i];
  bf16x4 o;
  o[0] = (bf16)v.x; o[1] = (bf16)v.y; o[2] = (bf16)v.z; o[3] = (bf16)v.w;
  reinterpret_cast<bf16x4*>(dst)[i] = o;
}

// ---------------- GEMM v3: BK=64 + both-sides XOR chunk swizzle ----------------
template<int MODE, int N_TOTAL>
__global__ __launch_bounds__(256)
void gemm2_kernel(const bf16* __restrict__ A, const bf16* __restrict__ W,
                  const float* __restrict__ b0, const float* __restrict__ b1,
                  const float* __restrict__ b2, float qalpha,
                  void* __restrict__ out0, void* __restrict__ out1, void* __restrict__ out2)
{
  __shared__ bf16 As[128 * 64];
  __shared__ bf16 Bs[128 * 64];
  const int tid  = threadIdx.x;
  const int lane = tid & 63;
  const int wave = tid >> 6;
  const int m0 = blockIdx.y * 128;
  const int n0 = blockIdx.x * 128;
  const int wm = (wave >> 1) * 64;
  const int wn = (wave & 1) * 64;
  const int qd = lane >> 4;
  const int lm = lane & 15;

  const int srow8  = lane >> 3;
  const int schunk = ((lane & 7) ^ srow8) * 8;
  const bf16* gA = A + (size_t)(m0 + wave * 32 + srow8) * 1024 + schunk;
  const bf16* gB = W + (size_t)(n0 + wave * 32 + srow8) * 1024 + schunk;
  bf16* lA = As + wave * 32 * 64;
  bf16* lB = Bs + wave * 32 * 64;

  f32x4 acc[4][4] = {};
  const int xs = lm & 7;

  for (int k0 = 0; k0 < 1024; k0 += 64) {
#pragma unroll
    for (int j = 0; j < 4; j++) {
      gld16(gA + (size_t)j * 8 * 1024 + k0, lA + j * 8 * 64);
      gld16(gB + (size_t)j * 8 * 1024 + k0, lB + j * 8 * 64);
    }
    __syncthreads();
    bf16x8 af[4][2], bfr[4][2];
#pragma unroll
    for (int i = 0; i < 4; i++) {
#pragma unroll
      for (int kk = 0; kk < 2; kk++) {
        af[i][kk]  = *(const bf16x8*)&As[(wm + i * 16 + lm) * 64 + (((kk * 4 + qd) ^ xs) * 8)];
        bfr[i][kk] = *(const bf16x8*)&Bs[(wn + i * 16 + lm) * 64 + (((kk * 4 + qd) ^ xs) * 8)];
      }
    }
#pragma unroll
    for (int kk = 0; kk < 2; kk++)
#pragma unroll
      for (int im = 0; im < 4; im++)
#pragma unroll
        for (int in = 0; in < 4; in++)
          acc[im][in] = __builtin_amdgcn_mfma_f32_16x16x32_bf16(af[im][kk], bfr[in][kk], acc[im][in], 0, 0, 0);
    __syncthreads();
  }

  const int seg = n0 >> 10;
  const float* bias = (MODE == 0) ? b0 : (seg == 0 ? b0 : (seg == 1 ? b1 : b2));
  const float alpha = (MODE == 1 && seg == 0) ? qalpha : 1.0f;

#pragma unroll
  for (int im = 0; im < 4; im++) {
#pragma unroll
    for (int in = 0; in < 4; in++) {
      const int n  = n0 + wn + in * 16 + lm;
      const int n1 = n & 1023;
      const float bv = bias[n1];
      const int mb = m0 + wm + im * 16 + qd * 4;
      if (MODE == 0) {
        float* o = (float*)out0;
#pragma unroll
        for (int r = 0; r < 4; r++)
          o[(size_t)(mb + r) * 1024 + n1] = acc[im][in][r] + bv;
      } else if (seg == 2) {
        const int bb = mb >> 11;
        const int t  = mb & 2047;
        bf16x4 pk;
#pragma unroll
        for (int r = 0; r < 4; r++) pk[r] = (bf16)(acc[im][in][r] + bv);
        *(bf16x4*)&((bf16*)out2)[((size_t)(bb * 1024 + n1)) * 2048 + t] = pk;
      } else {
        bf16* o = (bf16*)(seg == 0 ? out0 : out1);
#pragma unroll
        for (int r = 0; r < 4; r++)
          o[(size_t)(mb + r) * 1024 + n1] = (bf16)((acc[im][in][r] + bv) * alpha);
      }
    }
  }
}

// ---------------- O-projection GEMM: 64x128 tile -> grid (8,64)=512 blocks (2/CU) ----------------
__global__ __launch_bounds__(256)
void gemm_o_kernel(const bf16* __restrict__ A, const bf16* __restrict__ W,
                   const float* __restrict__ bias, float* __restrict__ out)
{
  __shared__ bf16 As[64 * 32];
  __shared__ bf16 Bs[128 * 32];
  const int tid  = threadIdx.x;
  const int lane = tid & 63;
  const int wave = tid >> 6;
  const int m0 = blockIdx.y * 64;
  const int n0 = blockIdx.x * 128;
  const int wm = (wave >> 1) * 32;
  const int wn = (wave & 1) * 64;
  const int qd = lane >> 4;
  const int lm = lane & 15;

  const int row4 = lane >> 2;
  const int col8 = (lane & 3) * 8;
  const bf16* gA0 = A + (size_t)(m0 + wave * 16 + row4) * 1024 + col8;
  const bf16* gB0 = W + (size_t)(n0 + wave * 32 + row4) * 1024 + col8;
  const bf16* gB1 = gB0 + (size_t)16 * 1024;
  bf16* lA0 = As + wave * 16 * 32;
  bf16* lB0 = Bs + (wave * 2 + 0) * 512;
  bf16* lB1 = Bs + (wave * 2 + 1) * 512;

  f32x4 acc[2][4] = {};

  for (int k0 = 0; k0 < 1024; k0 += 32) {
    gld16(gA0 + k0, lA0);
    gld16(gB0 + k0, lB0);
    gld16(gB1 + k0, lB1);
    __syncthreads();
    bf16x8 af[2], bfr[4];
#pragma unroll
    for (int i = 0; i < 2; i++)
      af[i]  = *(const bf16x8*)&As[(wm + i * 16 + lm) * 32 + qd * 8];
#pragma unroll
    for (int i = 0; i < 4; i++)
      bfr[i] = *(const bf16x8*)&Bs[(wn + i * 16 + lm) * 32 + qd * 8];
#pragma unroll
    for (int im = 0; im < 2; im++)
#pragma unroll
      for (int in = 0; in < 4; in++)
        acc[im][in] = __builtin_amdgcn_mfma_f32_16x16x32_bf16(af[im], bfr[in], acc[im][in], 0, 0, 0);
    __syncthreads();
  }

#pragma unroll
  for (int im = 0; im < 2; im++) {
#pragma unroll
    for (int in = 0; in < 4; in++) {
      const int n  = n0 + wn + in * 16 + lm;
      const float bv = bias[n];
      const int mb = m0 + wm + im * 16 + qd * 4;
#pragma unroll
      for (int r = 0; r < 4; r++)
        out[(size_t)(mb + r) * 1024 + n] = acc[im][in][r] + bv;
    }
  }
}

// ---------------- flash attention v7: 8 waves/block (16 q-rows per wave) ----------------
// Same tiles/LDS/P-redistribution as the round-2 kernel, but 512 threads:
// resident waves/CU double (8 -> 16, 2 -> 4 per SIMD) to attack the
// latency-bound profile (MfmaUtil 21 / VALUBusy 50 / neither saturated).
#define LK 72
__global__ __launch_bounds__(512)
void attn3_kernel(const bf16* __restrict__ Qg, const bf16* __restrict__ Kg,
                  const bf16* __restrict__ Vtg, const float* __restrict__ gate,
                  const float* __restrict__ pbt, bf16* __restrict__ ctx)
{
  __shared__ bf16 Ks[2][64 * LK];
  __shared__ bf16 Vs[2][64 * LK];
  __shared__ float pbs[2176];

  const int t0 = blockIdx.x * 128;
  const int h  = blockIdx.y;
  const int b  = blockIdx.z;
  const int tid  = threadIdx.x;
  const int lane = tid & 63;
  const int wave = tid >> 6;        // 0..7
  const int qd = lane >> 4;
  const int lm = lane & 15;

  for (int i = tid; i < 2176; i += 512) {
    int idx = i - t0 + 1920;
    pbs[i] = (idx >= 0 && idx < NDELTA) ? pbt[h * NDELTA + idx] : 0.0f;
  }

  // each wave owns 16 q-rows: q = t0 + wave*16 + lm
  const int rowoff = wave * 16 + lm;
  bf16x8 qf[2];
  float g;
  {
    const int q = t0 + rowoff;
    const bf16* qrow = Qg + (size_t)(b * T_SEQ + q) * E_DIM + h * D_DIM;
    qf[0] = *(const bf16x8*)(qrow + qd * 8);
    qf[1] = *(const bf16x8*)(qrow + 32 + qd * 8);
    g = gate[((size_t)(b * H_NUM + h)) * T_SEQ + q];
  }

  // staging: 512 threads, each 1 bf16x8 chunk of K and of V (64 rows x 64 cols)
  const int srow = tid >> 3;
  const int scol = (tid & 7) * 8;
  const bf16* kgp = Kg  + ((size_t)(b * T_SEQ) + srow) * E_DIM + h * D_DIM + scol;
  const bf16* vgp = Vtg + ((size_t)(b * 1024) + h * D_DIM + srow) * T_SEQ + scol;

  {
    bf16x8 a0 = *(const bf16x8*)kgp;
    bf16x8 c0 = *(const bf16x8*)vgp;
    *(bf16x8*)&Ks[0][srow * LK + scol] = a0;
    *(bf16x8*)&Vs[0][srow * LK + scol] = c0;
  }
  __syncthreads();

  f32x4 o[4] = {};
  float li = 0.0f;

  for (int it = 0; it < T_SEQ / 64; it++) {
    const int s0 = it * 64;
    const int buf = it & 1;
    const bool more = (it + 1 < T_SEQ / 64);
    bf16x8 nk0, nv0;
    if (more) {
      nk0 = *(const bf16x8*)(kgp + (size_t)(s0 + 64) * E_DIM);
      nv0 = *(const bf16x8*)(vgp + (s0 + 64));
    }

    bf16x8 kf[4][2];
#pragma unroll
    for (int mb = 0; mb < 4; mb++) {
      kf[mb][0] = *(const bf16x8*)&Ks[buf][(16 * mb + lm) * LK + qd * 8];
      kf[mb][1] = *(const bf16x8*)&Ks[buf][(16 * mb + lm) * LK + 32 + qd * 8];
    }

    f32x4 sc[4];
#pragma unroll
    for (int mb = 0; mb < 4; mb++) {
      f32x4 t = {};
      t = __builtin_amdgcn_mfma_f32_16x16x32_bf16(kf[mb][0], qf[0], t, 0, 0, 0);
      t = __builtin_amdgcn_mfma_f32_16x16x32_bf16(kf[mb][1], qf[1], t, 0, 0, 0);
      sc[mb] = t;
    }
    const int ib = s0 + 4 * qd + 127 - rowoff;
    float rs = 0.0f;
    unsigned wlo[4], whi[4];
#pragma unroll
    for (int mb = 0; mb < 4; mb++) {
      bf16x4 pk;
#pragma unroll
      for (int r = 0; r < 4; r++) {
        float p = __builtin_amdgcn_exp2f(sc[mb][r] + g * pbs[ib + 16 * mb + r]);
        rs += p;
        pk[r] = (bf16)p;
      }
      u32x2 pw = __builtin_bit_cast(u32x2, pk);
      wlo[mb] = pw[0]; whi[mb] = pw[1];
    }
    li += rs;
    bf16x8 pf[2];
    {
      unsigned a0 = wlo[0], b0v = wlo[1], a1 = whi[0], b1v = whi[1];
      qswap(a0, b0v);
      qswap(a1, b1v);
      u32x4 h0; h0[0] = a0; h0[1] = a1; h0[2] = b0v; h0[3] = b1v;
      pf[0] = __builtin_bit_cast(bf16x8, h0);
      unsigned c0 = wlo[2], d0v = wlo[3], c1 = whi[2], d1v = whi[3];
      qswap(c0, d0v);
      qswap(c1, d1v);
      u32x4 h1; h1[0] = c0; h1[1] = c1; h1[2] = d0v; h1[3] = d1v;
      pf[1] = __builtin_bit_cast(bf16x8, h1);
    }

#pragma unroll
    for (int db = 0; db < 4; db++) {
      bf16x8 vf0 = *(const bf16x8*)&Vs[buf][(16 * db + lm) * LK + qd * 8];
      bf16x8 vf1 = *(const bf16x8*)&Vs[buf][(16 * db + lm) * LK + 32 + qd * 8];
      o[db] = __builtin_amdgcn_mfma_f32_16x16x32_bf16(vf0, pf[0], o[db], 0, 0, 0);
      o[db] = __builtin_amdgcn_mfma_f32_16x16x32_bf16(vf1, pf[1], o[db], 0, 0, 0);
    }
    if (more) {
      *(bf16x8*)&Ks[buf ^ 1][srow * LK + scol] = nk0;
      *(bf16x8*)&Vs[buf ^ 1][srow * LK + scol] = nv0;
    }
    __syncthreads();
  }

  li += __shfl_xor(li, 16);
  li += __shfl_xor(li, 32);
  {
    const float inv = 1.0f / li;
    const int q = t0 + rowoff;
    bf16* obase = ctx + (size_t)(b * T_SEQ + q) * E_DIM + h * D_DIM + 4 * qd;
#pragma unroll
    for (int db = 0; db < 4; db++) {
      bf16x4 ov;
      ov[0] = (bf16)(o[db][0] * inv); ov[1] = (bf16)(o[db][1] * inv);
      ov[2] = (bf16)(o[db][2] * inv); ov[3] = (bf16)(o[db][3] * inv);
      *(bf16x4*)&obase[16 * db] = ov;
    }
  }
}

// ---------------- orchestration ----------------
extern "C" void kernel_launch(void* const* d_in, const int* in_sizes, int n_in,
                              void* d_out, int out_size, void* d_ws, size_t ws_size,
                              hipStream_t stream)
{
  const float* hs     = (const float*)d_in[0];
  const float* q_w    = (const float*)d_in[1];
  const float* q_b    = (const float*)d_in[2];
  const float* k_w    = (const float*)d_in[3];
  const float* k_b    = (const float*)d_in[4];
  const float* v_w    = (const float*)d_in[5];
  const float* v_b    = (const float*)d_in[6];
  const float* out_w  = (const float*)d_in[7];
  const float* out_b  = (const float*)d_in[8];
  const float* rel    = (const float*)d_in[9];
  const float* gconst = (const float*)d_in[10];
  const float* gru_w  = (const float*)d_in[11];
  const float* gru_b  = (const float*)d_in[12];

  char* p = (char*)d_ws;
  bf16* hsb  = (bf16*)p; p += (size_t)4096 * 1024 * 2;
  bf16* wcat = (bf16*)p; p += (size_t)3072 * 1024 * 2;
  bf16* wob  = (bf16*)p; p += (size_t)1024 * 1024 * 2;
  bf16* Qb   = (bf16*)p; p += (size_t)4096 * 1024 * 2;
  bf16* Kb   = (bf16*)p; p += (size_t)4096 * 1024 * 2;
  bf16* Vtb  = (bf16*)p; p += (size_t)2048 * 2048 * 2;
  bf16* ctxb = (bf16*)p; p += (size_t)4096 * 1024 * 2;
  float* gatep = (float*)p; p += (size_t)2 * H_NUM * T_SEQ * 4;
  float* pbt   = (float*)p; p += (size_t)H_NUM * NDELTA * 4;

  cast_gate_kernel<<<4096, 256, 0, stream>>>(hs, hsb, gru_w, gru_b, gconst, gatep);
  cast_w_kernel<<<dim3(1024, 5), 256, 0, stream>>>(q_w, k_w, v_w, out_w, wcat, wob, rel, pbt);

  const float qalpha = 0.125f * LOG2E;
  gemm2_kernel<1, 3072><<<dim3(24, 32), 256, 0, stream>>>(
      hsb, wcat, q_b, k_b, v_b, qalpha, Qb, Kb, Vtb);

  attn3_kernel<<<dim3(T_SEQ / 128, H_NUM, 2), 512, 0, stream>>>(Qb, Kb, Vtb, gatep, pbt, ctxb);

  gemm_o_kernel<<<dim3(8, 64), 256, 0, stream>>>(ctxb, wob, out_b, (float*)d_out);
}